// Round 1
// baseline (512.618 us; speedup 1.0000x reference)
//
#include <hip/hip_runtime.h>
#include <math.h>
#include <stdint.h>

typedef __bf16 bf16x8 __attribute__((ext_vector_type(8)));
typedef float f32x4 __attribute__((ext_vector_type(4)));
typedef unsigned int uint4v __attribute__((ext_vector_type(4)));

#define TWO_PI_F 6.28318530717958647692f
#define INV_4PI_F 0.079577471545947667884f

// packed-weight layout offsets in __bf16 elements inside d_ws
#define W1F_OFF 0
#define W1B_OFF 524288
#define W2F_OFF 1048576
#define W2B_OFF 1114112
#define W3F_OFF 1179648
#define W3B_OFF 1245184
#define W4F_OFF 1310720
#define W4B_OFF 1376256
#define PACK_CHUNKS_TOTAL 180224   // 65536*2 + 8192*6 chunks of 8 bf16

// async global->LDS, 16B per lane (global_load_lds_dwordx4)
typedef __attribute__((address_space(1))) const unsigned int GU32;
typedef __attribute__((address_space(3))) unsigned int LU32;
__device__ __forceinline__ void gll16(const __bf16* g, __bf16* l) {
  __builtin_amdgcn_global_load_lds((GU32*)(uintptr_t)(const void*)g,
                                   (LU32*)(unsigned int)(uintptr_t)(void*)l,
                                   16, 0, 0);
}

__device__ __forceinline__ float sin2pi(float t) {   // sin(2*pi*t)
  return __builtin_amdgcn_sinf(__builtin_amdgcn_fractf(t));
}
__device__ __forceinline__ float cos2pi(float t) {   // cos(2*pi*t)
  return __builtin_amdgcn_cosf(__builtin_amdgcn_fractf(t));
}

// ---------------------------------------------------------------------------
// Pack fp32 weights into bf16 MFMA B-operand tile order (unchanged).
// ---------------------------------------------------------------------------
__global__ void k_pack(const float* __restrict__ W1, const float* __restrict__ W2,
                       const float* __restrict__ W3, const float* __restrict__ W4,
                       __bf16* __restrict__ ws) {
  int gid = blockIdx.x * blockDim.x + threadIdx.x;
  if (gid >= PACK_CHUNKS_TOTAL) return;
  const float* W; int n, q, ct, kc; bool bwd; long dstoff;
  if (gid < 65536) {                       // W1 forward: K=2048, N=256
    int c = gid; n = c & 15; q = (c >> 4) & 3; ct = (c >> 6) & 15; kc = c >> 10;
    W = W1; bwd = false; dstoff = W1F_OFF + (long)c * 8;
  } else if (gid < 131072) {               // W1 backward: K=256, N=2048, ct-major
    int c = gid - 65536; n = c & 15; q = (c >> 4) & 3; kc = (c >> 6) & 7; ct = c >> 9;
    W = W1; bwd = true; dstoff = W1B_OFF + (long)c * 8;
  } else {                                 // W2..W4 fwd/bwd: K=N=256
    int g = gid - 131072; int r = g >> 13; int c = g & 8191;
    n = c & 15; q = (c >> 4) & 3; ct = (c >> 6) & 15; kc = c >> 10;
    W = (r < 2) ? W2 : (r < 4) ? W3 : W4; bwd = (r & 1);
    dstoff = W2F_OFF + (long)g * 8;
  }
  int k0 = kc * 32 + q * 8;
  int ngl = ct * 16 + n;
  bf16x8 v;
  #pragma unroll
  for (int j = 0; j < 8; ++j) {
    float f = bwd ? W[ngl * 256 + (k0 + j)] : W[(k0 + j) * 256 + ngl];
    v[j] = (__bf16)f;
  }
  *(bf16x8*)(ws + dstoff) = v;
}

// ---------------------------------------------------------------------------
// Biot-Savart: 1024-thread blocks; 256 points/block, 4 segment-chunks/point.
// seg/mid precomputed once into LDS; partial sums combined through LDS.
// 4 waves/SIMD (vs 1 before) to hide the dependent rsqrt chains.
// ---------------------------------------------------------------------------
__global__ void k_biot(const float* __restrict__ x, const float* __restrict__ bdry,
                       float* __restrict__ out, int N, int M) {
  __shared__ float se[512 * 3];
  __shared__ float sm[512 * 3];
  __shared__ float red[3 * 256 * 3];
  const int tid = threadIdx.x;
  for (int s = tid; s < M; s += 1024) {
    int sn = (s + 1 == M) ? 0 : s + 1;
    float b0 = bdry[s * 3 + 0], b1 = bdry[s * 3 + 1], b2 = bdry[s * 3 + 2];
    float c0 = bdry[sn * 3 + 0], c1 = bdry[sn * 3 + 1], c2 = bdry[sn * 3 + 2];
    se[s * 3 + 0] = c0 - b0; se[s * 3 + 1] = c1 - b1; se[s * 3 + 2] = c2 - b2;
    sm[s * 3 + 0] = 0.5f * (c0 + b0);
    sm[s * 3 + 1] = 0.5f * (c1 + b1);
    sm[s * 3 + 2] = 0.5f * (c2 + b2);
  }
  __syncthreads();
  const int p = tid & 255;
  const int q = tid >> 8;
  const int idx = blockIdx.x * 256 + p;
  float x0 = fminf(fmaxf(x[idx * 3 + 0], -1.f), 1.f);
  float x1 = fminf(fmaxf(x[idx * 3 + 1], -1.f), 1.f);
  float x2 = fminf(fmaxf(x[idx * 3 + 2], -1.f), 1.f);
  const int mq = M >> 2;          // 128
  float a0 = 0.f, a1 = 0.f, a2 = 0.f;
  #pragma unroll 4
  for (int it = 0; it < mq; ++it) {
    int s = q * mq + it;
    float e0 = se[s * 3 + 0], e1 = se[s * 3 + 1], e2 = se[s * 3 + 2];
    float d0 = x0 - sm[s * 3 + 0], d1 = x1 - sm[s * 3 + 1], d2 = x2 - sm[s * 3 + 2];
    float r2 = d0 * d0 + d1 * d1 + d2 * d2;
    float inv = rsqrtf(r2);
    float inv3 = inv * inv * inv;
    float n0 = e1 * d2 - e2 * d1;
    float n1 = e2 * d0 - e0 * d2;
    float n2 = e0 * d1 - e1 * d0;
    a0 = fmaf(n0, inv3, a0); a1 = fmaf(n1, inv3, a1); a2 = fmaf(n2, inv3, a2);
  }
  if (q) {
    float* rp = &red[((q - 1) * 256 + p) * 3];
    rp[0] = a0; rp[1] = a1; rp[2] = a2;
  }
  __syncthreads();
  if (q == 0) {
    #pragma unroll
    for (int c = 0; c < 3; ++c) {
      const float* rp = &red[(c * 256 + p) * 3];
      a0 += rp[0]; a1 += rp[1]; a2 += rp[2];
    }
    float* alpha = out + (size_t)7 * N;
    alpha[idx * 3 + 0] = a0 * INV_4PI_F;
    alpha[idx * 3 + 1] = a1 * INV_4PI_F;
    alpha[idx * 3 + 2] = a2 * INV_4PI_F;
  }
}

// ---------------------------------------------------------------------------
// Fused MLP forward + input-gradient backward.
// 256 threads = 4 waves; wave owns 16 rows. 176 x 16KB weight chunks streamed
// through a double-buffered LDS stage via global_load_lds:
//   per chunk: ISSUE(next) -> compute(cur) -> __syncthreads()
// (__syncthreads' implicit vmcnt(0) drain is the producer-side fence; the
//  stage latency hides under the 16 MFMAs + VALU of the current chunk.)
// ---------------------------------------------------------------------------
__launch_bounds__(256, 2)
__global__ void k_mlp(const float* __restrict__ x, const float* __restrict__ Brff,
                      const float* __restrict__ b1, const float* __restrict__ b2,
                      const float* __restrict__ b3, const float* __restrict__ b4,
                      const float* __restrict__ W5, const float* __restrict__ b5,
                      const __bf16* __restrict__ wsw, float* __restrict__ out, int N) {
  __shared__ __attribute__((aligned(16))) __bf16 sW[2][8192];   // 2 x 16KB dbuf
  __shared__ __attribute__((aligned(16))) __bf16 sConv[16384];  // 8KB/wave C->A conv

  const int tid  = threadIdx.x;
  const int wave = tid >> 6;
  const int lane = tid & 63;
  const int ml   = lane & 15;   // A-row m / B-col n / C-col n
  const int quad = lane >> 4;
  const int rowbase = blockIdx.x * 64 + wave * 16;

  __bf16* conv = sConv + wave * 4096;

  auto ISSUE = [&](int buf, const __bf16* src) {   // 16KB: 256 thr x 4 x 16B
    #pragma unroll
    for (int r = 0; r < 4; ++r) {
      int idx = tid + r * 256;
      gll16(src + (size_t)idx * 8, &sW[buf][0] + idx * 8);
    }
  };
  auto ISSUE_B1 = [&](int buf, int p) {            // two 8KB halves (p, p+64)
    const __bf16* base = wsw + W1B_OFF;
    #pragma unroll
    for (int r = 0; r < 4; ++r) {
      int idx = tid + r * 256;
      int half = idx >> 9;
      const __bf16* src = base + (size_t)(p + (half << 6)) * 4096 + (size_t)(idx & 511) * 8;
      gll16(src, &sW[buf][0] + idx * 8);
    }
  };

  // kick chunk 0 of W1F before anything else
  ISSUE(0, wsw + W1F_OFF);

  // x for A-side rows (row = rowbase + ml)
  float xa0, xa1, xa2;
  {
    const float* xp = x + (size_t)(rowbase + ml) * 3;
    xa0 = fminf(fmaxf(xp[0], -1.f), 1.f);
    xa1 = fminf(fmaxf(xp[1], -1.f), 1.f);
    xa2 = fminf(fmaxf(xp[2], -1.f), 1.f);
  }
  // x for C-side rows (row = rowbase + quad*4 + r)
  float xr[4][3];
  #pragma unroll
  for (int r = 0; r < 4; ++r) {
    const float* xp = x + (size_t)(rowbase + quad * 4 + r) * 3;
    #pragma unroll
    for (int i = 0; i < 3; ++i) xr[r][i] = fminf(fmaxf(xp[i], -1.f), 1.f);
  }

  f32x4 acc[16];
  bf16x8 h1f[8], h2f[8], h3f[8], gf[8];

  auto zero_acc = [&]() {
    #pragma unroll
    for (int ct = 0; ct < 16; ++ct) { f32x4 z = {0.f, 0.f, 0.f, 0.f}; acc[ct] = z; }
  };
  // C-layout (row=quad*4+r, col=ct*16+ml) -> conv index in A-frag tile order
  auto conv_widx = [&](int ct, int r) -> int {
    return (((ct >> 1) * 4 + ((ct & 1) << 1) + (ml >> 3)) * 16 + quad * 4 + r) * 8 + (ml & 7);
  };

  __syncthreads();   // chunk 0 resident

  // ---- Forward layer 1: y(RFF) @ W1, K=2048, 64 chunks ----
  zero_acc();
  {
    const __bf16* w1f = wsw + W1F_OFF;
    for (int kc = 0; kc < 64; ++kc) {
      int cur = kc & 1;
      const __bf16* nsrc = (kc < 63) ? w1f + (size_t)(kc + 1) * 8192 : wsw + W2F_OFF;
      ISSUE(cur ^ 1, nsrc);
      int kbase = kc * 32 + quad * 8;
      int cb = kbase & 1023;
      const float* B0p = Brff + cb;
      const float* B1p = Brff + 1024 + cb;
      const float* B2p = Brff + 2048 + cb;
      bf16x8 af;
      bool issin = (kc < 32);
      #pragma unroll
      for (int j = 0; j < 8; ++j) {
        float t = xa0 * B0p[j] + xa1 * B1p[j] + xa2 * B2p[j];
        float v = issin ? sin2pi(t) : cos2pi(t);
        af[j] = (__bf16)v;
      }
      #pragma unroll
      for (int ct = 0; ct < 16; ++ct) {
        bf16x8 bfr = *(const bf16x8*)(sW[cur] + (ct * 4 + quad) * 128 + ml * 8);
        acc[ct] = __builtin_amdgcn_mfma_f32_16x16x32_bf16(af, bfr, acc[ct], 0, 0, 0);
      }
      __syncthreads();
    }
  }

  auto epilogue_h = [&](const float* __restrict__ bias, bf16x8* hf) {
    #pragma unroll
    for (int ct = 0; ct < 16; ++ct) {
      float bcol = bias[ct * 16 + ml];
      #pragma unroll
      for (int r = 0; r < 4; ++r) {
        float z = acc[ct][r] + bcol;
        float h = fmaxf(z, 0.f) + __logf(1.f + __expf(-fabsf(z)));  // softplus
        conv[conv_widx(ct, r)] = (__bf16)h;
      }
    }
    #pragma unroll
    for (int ks = 0; ks < 8; ++ks)
      hf[ks] = *(const bf16x8*)(conv + (ks * 4 + quad) * 128 + ml * 8);
  };

  // K=256,N=256 GEMM over 8 chunks; prefetches next layer's chunk 0 at kc==7.
  auto gemm256 = [&](const bf16x8* afr, const __bf16* wsrc,
                     const __bf16* nsrc, bool nextB1) {
    zero_acc();
    #pragma unroll
    for (int kc = 0; kc < 8; ++kc) {
      int cur = kc & 1;
      if (kc < 7)      ISSUE(cur ^ 1, wsrc + (size_t)(kc + 1) * 8192);
      else if (nextB1) ISSUE_B1(cur ^ 1, 0);
      else             ISSUE(cur ^ 1, nsrc);
      #pragma unroll
      for (int ct = 0; ct < 16; ++ct) {
        bf16x8 bfr = *(const bf16x8*)(sW[cur] + (ct * 4 + quad) * 128 + ml * 8);
        acc[ct] = __builtin_amdgcn_mfma_f32_16x16x32_bf16(afr[kc], bfr, acc[ct], 0, 0, 0);
      }
      __syncthreads();
    }
  };

  epilogue_h(b1, h1f);
  gemm256(h1f, wsw + W2F_OFF, wsw + W3F_OFF, false);
  epilogue_h(b2, h2f);
  gemm256(h2f, wsw + W3F_OFF, wsw + W4F_OFF, false);
  epilogue_h(b3, h3f);
  gemm256(h3f, wsw + W4F_OFF, wsw + W4B_OFF, false);

  // ---- Layer-4 epilogue: f head + g4 = sigma(z4)*W5 ----
  {
    float fpart[4] = {0.f, 0.f, 0.f, 0.f};
    #pragma unroll
    for (int ct = 0; ct < 16; ++ct) {
      float bcol = b4[ct * 16 + ml];
      float w5   = W5[ct * 16 + ml];
      #pragma unroll
      for (int r = 0; r < 4; ++r) {
        float z = acc[ct][r] + bcol;
        float ez = __expf(-fabsf(z));
        float sp = fmaxf(z, 0.f) + __logf(1.f + ez);
        float sig = (z >= 0.f) ? 1.f / (1.f + ez) : ez / (1.f + ez);
        fpart[r] += sp * w5;
        conv[conv_widx(ct, r)] = (__bf16)(sig * w5);
      }
    }
    #pragma unroll
    for (int r = 0; r < 4; ++r) {
      float v = fpart[r];
      #pragma unroll
      for (int m = 1; m < 16; m <<= 1) v += __shfl_xor(v, m, 64);
      if (ml == 0) out[rowbase + quad * 4 + r] = v + b5[0];
    }
    #pragma unroll
    for (int ks = 0; ks < 8; ++ks)
      gf[ks] = *(const bf16x8*)(conv + (ks * 4 + quad) * 128 + ml * 8);
  }

  // ---- Backward: g_{l-1} = (g_l @ W_l^T) * sigma(z_{l-1}); sigma = 1 - exp(-h) ----
  auto epilogue_g = [&](const bf16x8* hf) {
    #pragma unroll
    for (int ct = 0; ct < 16; ++ct) {
      #pragma unroll
      for (int r = 0; r < 4; ++r) conv[conv_widx(ct, r)] = (__bf16)acc[ct][r];
    }
    #pragma unroll
    for (int ks = 0; ks < 8; ++ks) {
      bf16x8 t = *(const bf16x8*)(conv + (ks * 4 + quad) * 128 + ml * 8);
      bf16x8 o;
      #pragma unroll
      for (int j = 0; j < 8; ++j) {
        float gp = (float)t[j];
        float h  = (float)hf[ks][j];
        o[j] = (__bf16)(gp * (1.f - __expf(-h)));
      }
      gf[ks] = o;
    }
  };

  gemm256(gf, wsw + W4B_OFF, wsw + W3B_OFF, false); epilogue_g(h3f);
  gemm256(gf, wsw + W3B_OFF, wsw + W2B_OFF, false); epilogue_g(h2f);
  gemm256(gf, wsw + W2B_OFF, nullptr, true);        epilogue_g(h1f);

  // ---- Backward L1: dy = g1 @ W1^T fused with dproj & dx; cols paired (c, c+1024) ----
  float dxa[4][3];
  #pragma unroll
  for (int r = 0; r < 4; ++r) { dxa[r][0] = 0.f; dxa[r][1] = 0.f; dxa[r][2] = 0.f; }

  for (int p = 0; p < 64; ++p) {
    int cur = p & 1;
    if (p < 63) ISSUE_B1(cur ^ 1, p + 1);
    f32x4 aA = {0.f, 0.f, 0.f, 0.f}, aB = {0.f, 0.f, 0.f, 0.f};
    #pragma unroll
    for (int ks = 0; ks < 8; ++ks) {
      bf16x8 bA = *(const bf16x8*)(sW[cur] + (ks * 4 + quad) * 128 + ml * 8);
      bf16x8 bB = *(const bf16x8*)(sW[cur] + 4096 + (ks * 4 + quad) * 128 + ml * 8);
      aA = __builtin_amdgcn_mfma_f32_16x16x32_bf16(gf[ks], bA, aA, 0, 0, 0);
      aB = __builtin_amdgcn_mfma_f32_16x16x32_bf16(gf[ks], bB, aB, 0, 0, 0);
    }
    int c = p * 16 + ml;
    float B0 = Brff[c], B1 = Brff[1024 + c], B2 = Brff[2048 + c];
    #pragma unroll
    for (int r = 0; r < 4; ++r) {
      float t = xr[r][0] * B0 + xr[r][1] * B1 + xr[r][2] * B2;
      float tf = __builtin_amdgcn_fractf(t);
      float sn = __builtin_amdgcn_sinf(tf);
      float cs = __builtin_amdgcn_cosf(tf);
      float dp = aA[r] * cs - aB[r] * sn;
      dxa[r][0] = fmaf(dp, B0, dxa[r][0]);
      dxa[r][1] = fmaf(dp, B1, dxa[r][1]);
      dxa[r][2] = fmaf(dp, B2, dxa[r][2]);
    }
    __syncthreads();
  }

  #pragma unroll
  for (int r = 0; r < 4; ++r) {
    #pragma unroll
    for (int i = 0; i < 3; ++i) {
      float v = dxa[r][i] * TWO_PI_F;
      #pragma unroll
      for (int m = 1; m < 16; m <<= 1) v += __shfl_xor(v, m, 64);
      if (ml == 0) {
        int row = rowbase + quad * 4 + r;
        out[(size_t)4 * N + row * 3 + i] = v;                                   // df
        out[(size_t)N + row * 3 + i] = v + out[(size_t)7 * N + row * 3 + i];    // current
      }
    }
  }
}

extern "C" void kernel_launch(void* const* d_in, const int* in_sizes, int n_in,
                              void* d_out, int out_size, void* d_ws, size_t ws_size,
                              hipStream_t stream) {
  const float* x    = (const float*)d_in[0];
  const float* bdry = (const float*)d_in[1];
  const float* Brff = (const float*)d_in[2];
  const float* W1   = (const float*)d_in[3];
  const float* b1   = (const float*)d_in[4];
  const float* W2   = (const float*)d_in[5];
  const float* b2   = (const float*)d_in[6];
  const float* W3   = (const float*)d_in[7];
  const float* b3   = (const float*)d_in[8];
  const float* W4   = (const float*)d_in[9];
  const float* b4   = (const float*)d_in[10];
  const float* W5   = (const float*)d_in[11];
  const float* b5   = (const float*)d_in[12];
  float* out = (float*)d_out;
  __bf16* ws = (__bf16*)d_ws;
  int N = in_sizes[0] / 3;   // 65536
  int M = in_sizes[1] / 3;   // 512

  k_pack<<<(PACK_CHUNKS_TOTAL + 255) / 256, 256, 0, stream>>>(W1, W2, W3, W4, ws);
  k_biot<<<N / 256, 1024, 0, stream>>>(x, bdry, out, N, M);
  k_mlp<<<N / 64, 256, 0, stream>>>(x, Brff, b1, b2, b3, b4, W5, b5, ws, out, N);
}

// Round 2
// 473.551 us; speedup vs baseline: 1.0825x; 1.0825x over previous
//
#include <hip/hip_runtime.h>
#include <math.h>
#include <stdint.h>

typedef __bf16 bf16x8 __attribute__((ext_vector_type(8)));
typedef float f32x4 __attribute__((ext_vector_type(4)));

#define TWO_PI_F 6.28318530717958647692f
#define INV_4PI_F 0.079577471545947667884f

// packed-weight layout offsets in __bf16 elements inside d_ws
#define W1F_OFF 0
#define W1B_OFF 524288
#define W2F_OFF 1048576
#define W2B_OFF 1114112
#define W3F_OFF 1179648
#define W3B_OFF 1245184
#define W4F_OFF 1310720
#define W4B_OFF 1376256
#define PACK_CHUNKS_TOTAL 180224   // 65536*2 + 8192*6 chunks of 8 bf16
#define PACK_BLOCKS 176            // PACK_CHUNKS_TOTAL / 1024

// async global->LDS, 16B per lane (global_load_lds_dwordx4)
typedef __attribute__((address_space(1))) const unsigned int GU32;
typedef __attribute__((address_space(3))) unsigned int LU32;
__device__ __forceinline__ void gll16(const __bf16* g, __bf16* l) {
  __builtin_amdgcn_global_load_lds((GU32*)(uintptr_t)(const void*)g,
                                   (LU32*)(unsigned int)(uintptr_t)(void*)l,
                                   16, 0, 0);
}

__device__ __forceinline__ float sin2pi(float t) {   // sin(2*pi*t)
  return __builtin_amdgcn_sinf(__builtin_amdgcn_fractf(t));
}
__device__ __forceinline__ float cos2pi(float t) {   // cos(2*pi*t)
  return __builtin_amdgcn_cosf(__builtin_amdgcn_fractf(t));
}

// ---------------------------------------------------------------------------
// Fused prep kernel: blocks [0,176) pack weights into bf16 MFMA tile order,
// blocks [176, 176+N/256) compute Biot-Savart alpha. One launch -> overlap.
// ---------------------------------------------------------------------------
__launch_bounds__(1024)
__global__ void k_prep(const float* __restrict__ W1, const float* __restrict__ W2,
                       const float* __restrict__ W3, const float* __restrict__ W4,
                       const float* __restrict__ x, const float* __restrict__ bdry,
                       float* __restrict__ out, __bf16* __restrict__ ws,
                       int N, int M) {
  __shared__ float se[512 * 3];
  __shared__ float sm[512 * 3];
  __shared__ float red[3 * 256 * 3];

  if (blockIdx.x < PACK_BLOCKS) {
    // ---- weight pack ----
    int gid = blockIdx.x * 1024 + threadIdx.x;
    if (gid >= PACK_CHUNKS_TOTAL) return;
    const float* W; int n, q, ct, kc; bool bwd; long dstoff;
    if (gid < 65536) {                       // W1 forward: K=2048, N=256
      int c = gid; n = c & 15; q = (c >> 4) & 3; ct = (c >> 6) & 15; kc = c >> 10;
      W = W1; bwd = false; dstoff = W1F_OFF + (long)c * 8;
    } else if (gid < 131072) {               // W1 backward: K=256, N=2048, ct-major
      int c = gid - 65536; n = c & 15; q = (c >> 4) & 3; kc = (c >> 6) & 7; ct = c >> 9;
      W = W1; bwd = true; dstoff = W1B_OFF + (long)c * 8;
    } else {                                 // W2..W4 fwd/bwd: K=N=256
      int g = gid - 131072; int r = g >> 13; int c = g & 8191;
      n = c & 15; q = (c >> 4) & 3; ct = (c >> 6) & 15; kc = c >> 10;
      W = (r < 2) ? W2 : (r < 4) ? W3 : W4; bwd = (r & 1);
      dstoff = W2F_OFF + (long)g * 8;
    }
    int k0 = kc * 32 + q * 8;
    int ngl = ct * 16 + n;
    bf16x8 v;
    #pragma unroll
    for (int j = 0; j < 8; ++j) {
      float f = bwd ? W[ngl * 256 + (k0 + j)] : W[(k0 + j) * 256 + ngl];
      v[j] = (__bf16)f;
    }
    *(bf16x8*)(ws + dstoff) = v;
    return;
  }

  // ---- Biot-Savart: 256 points/block, 4 segment-chunks/point ----
  const int tid = threadIdx.x;
  for (int s = tid; s < M; s += 1024) {
    int sn = (s + 1 == M) ? 0 : s + 1;
    float b0 = bdry[s * 3 + 0], b1 = bdry[s * 3 + 1], b2 = bdry[s * 3 + 2];
    float c0 = bdry[sn * 3 + 0], c1 = bdry[sn * 3 + 1], c2 = bdry[sn * 3 + 2];
    se[s * 3 + 0] = c0 - b0; se[s * 3 + 1] = c1 - b1; se[s * 3 + 2] = c2 - b2;
    sm[s * 3 + 0] = 0.5f * (c0 + b0);
    sm[s * 3 + 1] = 0.5f * (c1 + b1);
    sm[s * 3 + 2] = 0.5f * (c2 + b2);
  }
  __syncthreads();
  const int p = tid & 255;
  const int q = tid >> 8;
  const int idx = (blockIdx.x - PACK_BLOCKS) * 256 + p;
  float x0 = fminf(fmaxf(x[idx * 3 + 0], -1.f), 1.f);
  float x1 = fminf(fmaxf(x[idx * 3 + 1], -1.f), 1.f);
  float x2 = fminf(fmaxf(x[idx * 3 + 2], -1.f), 1.f);
  const int mq = M >> 2;          // 128
  float a0 = 0.f, a1 = 0.f, a2 = 0.f;
  #pragma unroll 4
  for (int it = 0; it < mq; ++it) {
    int s = q * mq + it;
    float e0 = se[s * 3 + 0], e1 = se[s * 3 + 1], e2 = se[s * 3 + 2];
    float d0 = x0 - sm[s * 3 + 0], d1 = x1 - sm[s * 3 + 1], d2 = x2 - sm[s * 3 + 2];
    float r2 = d0 * d0 + d1 * d1 + d2 * d2;
    float inv = rsqrtf(r2);
    float inv3 = inv * inv * inv;
    float n0 = e1 * d2 - e2 * d1;
    float n1 = e2 * d0 - e0 * d2;
    float n2 = e0 * d1 - e1 * d0;
    a0 = fmaf(n0, inv3, a0); a1 = fmaf(n1, inv3, a1); a2 = fmaf(n2, inv3, a2);
  }
  if (q) {
    float* rp = &red[((q - 1) * 256 + p) * 3];
    rp[0] = a0; rp[1] = a1; rp[2] = a2;
  }
  __syncthreads();
  if (q == 0) {
    #pragma unroll
    for (int c = 0; c < 3; ++c) {
      const float* rp = &red[(c * 256 + p) * 3];
      a0 += rp[0]; a1 += rp[1]; a2 += rp[2];
    }
    float* alpha = out + (size_t)7 * N;
    alpha[idx * 3 + 0] = a0 * INV_4PI_F;
    alpha[idx * 3 + 1] = a1 * INV_4PI_F;
    alpha[idx * 3 + 2] = a2 * INV_4PI_F;
  }
}

// ---------------------------------------------------------------------------
// Fused MLP forward + input-gradient backward.
// 512 threads = 8 waves; wave owns 16 rows -> 128 rows/block. Each 16KB weight
// chunk feeds 8 waves (2x the MFMA work per stage vs the 4-wave version) and
// the per-row weight stream halves. LDS: 2x16KB weight dbuf + 32KB conv
// (time-shared between wave-groups 0-3 / 4-7 at epilogues) = 64KB ->
// 2 blocks/CU = 4 waves/SIMD.
//   per chunk: ISSUE(next) -> compute(cur) -> __syncthreads()
// ---------------------------------------------------------------------------
__launch_bounds__(512, 4)
__global__ void k_mlp(const float* __restrict__ x, const float* __restrict__ Brff,
                      const float* __restrict__ b1, const float* __restrict__ b2,
                      const float* __restrict__ b3, const float* __restrict__ b4,
                      const float* __restrict__ W5, const float* __restrict__ b5,
                      const __bf16* __restrict__ wsw, float* __restrict__ out, int N) {
  __shared__ __attribute__((aligned(16))) __bf16 sW[2][8192];   // 2 x 16KB dbuf
  __shared__ __attribute__((aligned(16))) __bf16 sConv[16384];  // 8KB/wave x 4 slots

  const int tid  = threadIdx.x;
  const int wave = tid >> 6;
  const int grp  = wave >> 2;   // epilogue time-share group
  const int lane = tid & 63;
  const int ml   = lane & 15;   // A-row m / B-col n / C-col n
  const int quad = lane >> 4;
  const int rowbase = blockIdx.x * 128 + wave * 16;

  __bf16* conv = sConv + (wave & 3) * 4096;

  auto ISSUE = [&](int buf, const __bf16* src) {   // 16KB: 512 thr x 2 x 16B
    #pragma unroll
    for (int r = 0; r < 2; ++r) {
      int idx = tid + r * 512;
      gll16(src + (size_t)idx * 8, &sW[buf][0] + idx * 8);
    }
  };
  auto ISSUE_B1 = [&](int buf, int p) {            // two 8KB halves (p, p+64)
    const __bf16* base = wsw + W1B_OFF;
    #pragma unroll
    for (int r = 0; r < 2; ++r) {
      int idx = tid + r * 512;
      int half = idx >> 9;
      const __bf16* src = base + (size_t)(p + (half << 6)) * 4096 + (size_t)(idx & 511) * 8;
      gll16(src, &sW[buf][0] + idx * 8);
    }
  };

  // kick chunk 0 of W1F before anything else
  ISSUE(0, wsw + W1F_OFF);

  // x for A-side rows (row = rowbase + ml)
  float xa0, xa1, xa2;
  {
    const float* xp = x + (size_t)(rowbase + ml) * 3;
    xa0 = fminf(fmaxf(xp[0], -1.f), 1.f);
    xa1 = fminf(fmaxf(xp[1], -1.f), 1.f);
    xa2 = fminf(fmaxf(xp[2], -1.f), 1.f);
  }
  // x for C-side rows (row = rowbase + quad*4 + r)
  float xr[4][3];
  #pragma unroll
  for (int r = 0; r < 4; ++r) {
    const float* xp = x + (size_t)(rowbase + quad * 4 + r) * 3;
    #pragma unroll
    for (int i = 0; i < 3; ++i) xr[r][i] = fminf(fmaxf(xp[i], -1.f), 1.f);
  }

  f32x4 acc[16];
  bf16x8 h1f[8], h2f[8], h3f[8], gf[8];

  auto zero_acc = [&]() {
    #pragma unroll
    for (int ct = 0; ct < 16; ++ct) { f32x4 z = {0.f, 0.f, 0.f, 0.f}; acc[ct] = z; }
  };
  // C-layout (row=quad*4+r, col=ct*16+ml) -> conv index in A-frag tile order
  auto conv_widx = [&](int ct, int r) -> int {
    return (((ct >> 1) * 4 + ((ct & 1) << 1) + (ml >> 3)) * 16 + quad * 4 + r) * 8 + (ml & 7);
  };

  __syncthreads();   // chunk 0 resident

  // ---- Forward layer 1: y(RFF) @ W1, K=2048, 64 chunks ----
  zero_acc();
  {
    const __bf16* w1f = wsw + W1F_OFF;
    for (int kc = 0; kc < 64; ++kc) {
      int cur = kc & 1;
      const __bf16* nsrc = (kc < 63) ? w1f + (size_t)(kc + 1) * 8192 : wsw + W2F_OFF;
      ISSUE(cur ^ 1, nsrc);
      int kbase = kc * 32 + quad * 8;
      int cb = kbase & 1023;
      const float* B0p = Brff + cb;
      const float* B1p = Brff + 1024 + cb;
      const float* B2p = Brff + 2048 + cb;
      bf16x8 af;
      bool issin = (kc < 32);
      #pragma unroll
      for (int j = 0; j < 8; ++j) {
        float t = xa0 * B0p[j] + xa1 * B1p[j] + xa2 * B2p[j];
        float v = issin ? sin2pi(t) : cos2pi(t);
        af[j] = (__bf16)v;
      }
      #pragma unroll
      for (int ct = 0; ct < 16; ++ct) {
        bf16x8 bfr = *(const bf16x8*)(sW[cur] + (ct * 4 + quad) * 128 + ml * 8);
        acc[ct] = __builtin_amdgcn_mfma_f32_16x16x32_bf16(af, bfr, acc[ct], 0, 0, 0);
      }
      __syncthreads();
    }
  }

  // softplus into acc in-place (pure VALU, all 8 waves), then time-shared
  // LDS transpose: group 0 uses conv slots, barrier, group 1, barrier.
  auto epilogue_h = [&](const float* __restrict__ bias, bf16x8* hf) {
    #pragma unroll
    for (int ct = 0; ct < 16; ++ct) {
      float bcol = bias[ct * 16 + ml];
      #pragma unroll
      for (int r = 0; r < 4; ++r) {
        float z = acc[ct][r] + bcol;
        acc[ct][r] = fmaxf(z, 0.f) + __logf(1.f + __expf(-fabsf(z)));  // softplus
      }
    }
    #pragma unroll
    for (int g = 0; g < 2; ++g) {
      if (grp == g) {
        #pragma unroll
        for (int ct = 0; ct < 16; ++ct)
          #pragma unroll
          for (int r = 0; r < 4; ++r)
            conv[conv_widx(ct, r)] = (__bf16)acc[ct][r];
        #pragma unroll
        for (int ks = 0; ks < 8; ++ks)
          hf[ks] = *(const bf16x8*)(conv + (ks * 4 + quad) * 128 + ml * 8);
      }
      __syncthreads();
    }
  };

  // K=256,N=256 GEMM over 8 chunks; prefetches next layer's chunk 0 at kc==7.
  auto gemm256 = [&](const bf16x8* afr, const __bf16* wsrc,
                     const __bf16* nsrc, bool nextB1) {
    zero_acc();
    #pragma unroll
    for (int kc = 0; kc < 8; ++kc) {
      int cur = kc & 1;
      if (kc < 7)      ISSUE(cur ^ 1, wsrc + (size_t)(kc + 1) * 8192);
      else if (nextB1) ISSUE_B1(cur ^ 1, 0);
      else             ISSUE(cur ^ 1, nsrc);
      #pragma unroll
      for (int ct = 0; ct < 16; ++ct) {
        bf16x8 bfr = *(const bf16x8*)(sW[cur] + (ct * 4 + quad) * 128 + ml * 8);
        acc[ct] = __builtin_amdgcn_mfma_f32_16x16x32_bf16(afr[kc], bfr, acc[ct], 0, 0, 0);
      }
      __syncthreads();
    }
  };

  epilogue_h(b1, h1f);
  gemm256(h1f, wsw + W2F_OFF, wsw + W3F_OFF, false);
  epilogue_h(b2, h2f);
  gemm256(h2f, wsw + W3F_OFF, wsw + W4F_OFF, false);
  epilogue_h(b3, h3f);
  gemm256(h3f, wsw + W4F_OFF, wsw + W4B_OFF, false);

  // ---- Layer-4 epilogue: f head + g4 = sigma(z4)*W5 ----
  {
    float fpart[4] = {0.f, 0.f, 0.f, 0.f};
    #pragma unroll
    for (int ct = 0; ct < 16; ++ct) {
      float bcol = b4[ct * 16 + ml];
      float w5   = W5[ct * 16 + ml];
      #pragma unroll
      for (int r = 0; r < 4; ++r) {
        float z = acc[ct][r] + bcol;
        float ez = __expf(-fabsf(z));
        float sp = fmaxf(z, 0.f) + __logf(1.f + ez);
        float sig = (z >= 0.f) ? 1.f / (1.f + ez) : ez / (1.f + ez);
        fpart[r] += sp * w5;
        acc[ct][r] = sig * w5;
      }
    }
    #pragma unroll
    for (int r = 0; r < 4; ++r) {
      float v = fpart[r];
      #pragma unroll
      for (int m = 1; m < 16; m <<= 1) v += __shfl_xor(v, m, 64);
      if (ml == 0) out[rowbase + quad * 4 + r] = v + b5[0];
    }
    #pragma unroll
    for (int g = 0; g < 2; ++g) {
      if (grp == g) {
        #pragma unroll
        for (int ct = 0; ct < 16; ++ct)
          #pragma unroll
          for (int r = 0; r < 4; ++r)
            conv[conv_widx(ct, r)] = (__bf16)acc[ct][r];
        #pragma unroll
        for (int ks = 0; ks < 8; ++ks)
          gf[ks] = *(const bf16x8*)(conv + (ks * 4 + quad) * 128 + ml * 8);
      }
      __syncthreads();
    }
  }

  // ---- Backward: g_{l-1} = (g_l @ W_l^T) * sigma(z_{l-1}); sigma = 1 - exp(-h) ----
  auto epilogue_g = [&](const bf16x8* hf) {
    #pragma unroll
    for (int g = 0; g < 2; ++g) {
      if (grp == g) {
        #pragma unroll
        for (int ct = 0; ct < 16; ++ct)
          #pragma unroll
          for (int r = 0; r < 4; ++r)
            conv[conv_widx(ct, r)] = (__bf16)acc[ct][r];
        #pragma unroll
        for (int ks = 0; ks < 8; ++ks)
          gf[ks] = *(const bf16x8*)(conv + (ks * 4 + quad) * 128 + ml * 8);
      }
      __syncthreads();
    }
    #pragma unroll
    for (int ks = 0; ks < 8; ++ks) {
      #pragma unroll
      for (int j = 0; j < 8; ++j) {
        float gp = (float)gf[ks][j];
        float h  = (float)hf[ks][j];
        gf[ks][j] = (__bf16)(gp * (1.f - __expf(-h)));
      }
    }
  };

  gemm256(gf, wsw + W4B_OFF, wsw + W3B_OFF, false); epilogue_g(h3f);
  gemm256(gf, wsw + W3B_OFF, wsw + W2B_OFF, false); epilogue_g(h2f);
  gemm256(gf, wsw + W2B_OFF, nullptr, true);        epilogue_g(h1f);

  // ---- Backward L1: dy = g1 @ W1^T fused with dproj & dx; cols paired (c, c+1024) ----
  float dxa[4][3];
  #pragma unroll
  for (int r = 0; r < 4; ++r) { dxa[r][0] = 0.f; dxa[r][1] = 0.f; dxa[r][2] = 0.f; }

  for (int p = 0; p < 64; ++p) {
    int cur = p & 1;
    if (p < 63) ISSUE_B1(cur ^ 1, p + 1);
    f32x4 aA = {0.f, 0.f, 0.f, 0.f}, aB = {0.f, 0.f, 0.f, 0.f};
    #pragma unroll
    for (int ks = 0; ks < 8; ++ks) {
      bf16x8 bA = *(const bf16x8*)(sW[cur] + (ks * 4 + quad) * 128 + ml * 8);
      bf16x8 bB = *(const bf16x8*)(sW[cur] + 4096 + (ks * 4 + quad) * 128 + ml * 8);
      aA = __builtin_amdgcn_mfma_f32_16x16x32_bf16(gf[ks], bA, aA, 0, 0, 0);
      aB = __builtin_amdgcn_mfma_f32_16x16x32_bf16(gf[ks], bB, aB, 0, 0, 0);
    }
    int c = p * 16 + ml;
    float B0 = Brff[c], B1 = Brff[1024 + c], B2 = Brff[2048 + c];
    #pragma unroll
    for (int r = 0; r < 4; ++r) {
      float t = xr[r][0] * B0 + xr[r][1] * B1 + xr[r][2] * B2;
      float tf = __builtin_amdgcn_fractf(t);
      float sn = __builtin_amdgcn_sinf(tf);
      float cs = __builtin_amdgcn_cosf(tf);
      float dp = aA[r] * cs - aB[r] * sn;
      dxa[r][0] = fmaf(dp, B0, dxa[r][0]);
      dxa[r][1] = fmaf(dp, B1, dxa[r][1]);
      dxa[r][2] = fmaf(dp, B2, dxa[r][2]);
    }
    __syncthreads();
  }

  #pragma unroll
  for (int r = 0; r < 4; ++r) {
    #pragma unroll
    for (int i = 0; i < 3; ++i) {
      float v = dxa[r][i] * TWO_PI_F;
      #pragma unroll
      for (int m = 1; m < 16; m <<= 1) v += __shfl_xor(v, m, 64);
      if (ml == 0) {
        int row = rowbase + quad * 4 + r;
        out[(size_t)4 * N + row * 3 + i] = v;                                   // df
        out[(size_t)N + row * 3 + i] = v + out[(size_t)7 * N + row * 3 + i];    // current
      }
    }
  }
}

extern "C" void kernel_launch(void* const* d_in, const int* in_sizes, int n_in,
                              void* d_out, int out_size, void* d_ws, size_t ws_size,
                              hipStream_t stream) {
  const float* x    = (const float*)d_in[0];
  const float* bdry = (const float*)d_in[1];
  const float* Brff = (const float*)d_in[2];
  const float* W1   = (const float*)d_in[3];
  const float* b1   = (const float*)d_in[4];
  const float* W2   = (const float*)d_in[5];
  const float* b2   = (const float*)d_in[6];
  const float* W3   = (const float*)d_in[7];
  const float* b3   = (const float*)d_in[8];
  const float* W4   = (const float*)d_in[9];
  const float* b4   = (const float*)d_in[10];
  const float* W5   = (const float*)d_in[11];
  const float* b5   = (const float*)d_in[12];
  float* out = (float*)d_out;
  __bf16* ws = (__bf16*)d_ws;
  int N = in_sizes[0] / 3;   // 65536
  int M = in_sizes[1] / 3;   // 512

  k_prep<<<PACK_BLOCKS + N / 256, 1024, 0, stream>>>(W1, W2, W3, W4, x, bdry, out, ws, N, M);
  k_mlp<<<N / 128, 512, 0, stream>>>(x, Brff, b1, b2, b3, b4, W5, b5, ws, out, N);
}